// Round 1
// baseline (310.613 us; speedup 1.0000x reference)
//
#include <hip/hip_runtime.h>

#define NB 16
#define NN 1024
#define NF 256
#define NEG_INF -1000000000.0f
#define SLOPE 0.2f

// ---------------------------------------------------------------------------
// Kernel 1: Wh = h @ W.  M=16384 (B*N), K=256, N=256. 64x64 tile, 4x4/thread.
// ---------------------------------------------------------------------------
__global__ __launch_bounds__(256) void wh_gemm(const float* __restrict__ A,
                                               const float* __restrict__ Wm,
                                               float* __restrict__ Wh) {
    __shared__ float As[16][68];   // [k][m], +4 pad keeps float4 alignment
    __shared__ float Bs[16][68];   // [k][n]
    const int t  = threadIdx.x;
    const int m0 = blockIdx.x * 64;
    const int n0 = blockIdx.y * 64;
    const int tx = t & 15, ty = t >> 4;

    float4 c0 = {0,0,0,0}, c1 = {0,0,0,0}, c2 = {0,0,0,0}, c3 = {0,0,0,0};

    const int ar = t >> 2;          // 0..63 : row within A tile
    const int ak = (t & 3) << 2;    // 0,4,8,12 : k-chunk
    const int bk = t >> 4;          // 0..15 : k row of B tile
    const int bn = (t & 15) << 2;   // 0..60 : n-chunk

    for (int k0 = 0; k0 < 256; k0 += 16) {
        float4 av = *(const float4*)(A + (m0 + ar) * 256 + k0 + ak);
        *(float4*)(&Bs[bk][bn]) = *(const float4*)(Wm + (k0 + bk) * 256 + n0 + bn);
        As[ak + 0][ar] = av.x;
        As[ak + 1][ar] = av.y;
        As[ak + 2][ar] = av.z;
        As[ak + 3][ar] = av.w;
        __syncthreads();
#pragma unroll
        for (int k = 0; k < 16; ++k) {
            float4 a4 = *(const float4*)(&As[k][ty << 2]);
            float4 b4 = *(const float4*)(&Bs[k][tx << 2]);
            c0.x += a4.x * b4.x; c0.y += a4.x * b4.y; c0.z += a4.x * b4.z; c0.w += a4.x * b4.w;
            c1.x += a4.y * b4.x; c1.y += a4.y * b4.y; c1.z += a4.y * b4.z; c1.w += a4.y * b4.w;
            c2.x += a4.z * b4.x; c2.y += a4.z * b4.y; c2.z += a4.z * b4.z; c2.w += a4.z * b4.w;
            c3.x += a4.w * b4.x; c3.y += a4.w * b4.y; c3.z += a4.w * b4.z; c3.w += a4.w * b4.w;
        }
        __syncthreads();
    }
    float* outp = Wh + (m0 + (ty << 2)) * 256 + n0 + (tx << 2);
    *(float4*)(outp + 0 * 256) = c0;
    *(float4*)(outp + 1 * 256) = c1;
    *(float4*)(outp + 2 * 256) = c2;
    *(float4*)(outp + 3 * 256) = c3;
}

// ---------------------------------------------------------------------------
// Kernel 2: f1 = Wh @ a1, f2 = Wh @ a2. One wave per row (4 rows/block).
// ---------------------------------------------------------------------------
__global__ __launch_bounds__(256) void f12_kernel(const float* __restrict__ Wh,
                                                  const float* __restrict__ a,
                                                  float* __restrict__ f1,
                                                  float* __restrict__ f2) {
    const int wid  = threadIdx.x >> 6;
    const int lane = threadIdx.x & 63;
    const int row  = blockIdx.x * 4 + wid;
    float4 w4 = *(const float4*)(Wh + row * 256 + lane * 4);
    float4 a1 = *(const float4*)(a + lane * 4);
    float4 a2 = *(const float4*)(a + 256 + lane * 4);
    float s1 = w4.x * a1.x + w4.y * a1.y + w4.z * a1.z + w4.w * a1.w;
    float s2 = w4.x * a2.x + w4.y * a2.y + w4.z * a2.z + w4.w * a2.w;
#pragma unroll
    for (int off = 32; off; off >>= 1) {
        s1 += __shfl_xor(s1, off);
        s2 += __shfl_xor(s2, off);
    }
    if (lane == 0) { f1[row] = s1; f2[row] = s2; }
}

// ---------------------------------------------------------------------------
// Kernel 3: masked softmax + h' = att @ Wh. Block = 16 i-rows x 256 f.
// ---------------------------------------------------------------------------
__global__ __launch_bounds__(256) void attn_kernel(const float* __restrict__ Wh,
                                                   const int* __restrict__ adj,
                                                   const float* __restrict__ f1g,
                                                   const float* __restrict__ f2g,
                                                   float* __restrict__ out) {
    __shared__ float s_f2[1024];
    __shared__ float s_f1[16];
    __shared__ float s_m[16];
    __shared__ float s_li[16];
    __shared__ float ws[256 * 20];   // [jj][il], row stride 20 (16B-aligned)

    const int t    = threadIdx.x;
    const int b    = blockIdx.y;
    const int i0   = blockIdx.x * 16;
    const int wid  = t >> 6;
    const int lane = t & 63;

    *(float4*)(s_f2 + t * 4) = *(const float4*)(f2g + (b << 10) + t * 4);
    if (t < 16) s_f1[t] = f1g[(b << 10) + i0 + t];
    __syncthreads();

    // ---- Phase 1: per-row online max / sum-exp. Wave wid owns rows wid*4..+3.
    for (int r = 0; r < 4; ++r) {
        const int il  = wid * 4 + r;
        const float f1i = s_f1[il];
        const int* arow = adj + (((b << 10) + i0 + il) << 10);
        float m = -3.0e38f, l = 0.f;
        for (int j = lane; j < 1024; j += 64) {
            float e;
            if (arow[j] == 0) e = NEG_INF;
            else {
                float x = f1i + s_f2[j];
                e = x > 0.f ? x : SLOPE * x;
            }
            float mn = fmaxf(m, e);
            l = l * __expf(m - mn) + __expf(e - mn);
            m = mn;
        }
#pragma unroll
        for (int off = 32; off; off >>= 1) {
            float mo = __shfl_xor(m, off);
            float lo = __shfl_xor(l, off);
            float mn = fmaxf(m, mo);
            l = l * __expf(m - mn) + lo * __expf(mo - mn);
            m = mn;
        }
        if (lane == 0) { s_m[il] = m; s_li[il] = 1.0f / l; }
    }
    __syncthreads();

    // ---- Phase 2: weights into LDS per 256-j tile, then 4i x 4f register tile.
    float4 acc0 = {0,0,0,0}, acc1 = {0,0,0,0}, acc2 = {0,0,0,0}, acc3 = {0,0,0,0};
    const int fg = lane << 2;       // f column base (0..252)
    const int ig = wid << 2;        // il base (0,4,8,12)

    for (int jt = 0; jt < 1024; jt += 256) {
        const float f2j = s_f2[jt + t];
#pragma unroll
        for (int il = 0; il < 16; ++il) {
            int av = adj[(((b << 10) + i0 + il) << 10) + jt + t];
            float x = s_f1[il] + f2j;
            float e = (av == 0) ? NEG_INF : (x > 0.f ? x : SLOPE * x);
            ws[t * 20 + il] = __expf(e - s_m[il]) * s_li[il];
        }
        __syncthreads();

        const float* whp = Wh + (((b << 10) + jt) << 8) + fg;
#pragma unroll 4
        for (int jj = 0; jj < 256; ++jj) {
            float4 wv = *(const float4*)(ws + jj * 20 + ig);
            float4 hv = *(const float4*)(whp + (jj << 8));
            acc0.x += wv.x * hv.x; acc0.y += wv.x * hv.y; acc0.z += wv.x * hv.z; acc0.w += wv.x * hv.w;
            acc1.x += wv.y * hv.x; acc1.y += wv.y * hv.y; acc1.z += wv.y * hv.z; acc1.w += wv.y * hv.w;
            acc2.x += wv.z * hv.x; acc2.y += wv.z * hv.y; acc2.z += wv.z * hv.z; acc2.w += wv.z * hv.w;
            acc3.x += wv.w * hv.x; acc3.y += wv.w * hv.y; acc3.z += wv.w * hv.z; acc3.w += wv.w * hv.w;
        }
        __syncthreads();
    }

    float* outp = out + (((b << 10) + i0 + ig) << 8) + fg;
    *(float4*)(outp + 0 * 256) = acc0;
    *(float4*)(outp + 1 * 256) = acc1;
    *(float4*)(outp + 2 * 256) = acc2;
    *(float4*)(outp + 3 * 256) = acc3;
}

// ---------------------------------------------------------------------------
extern "C" void kernel_launch(void* const* d_in, const int* in_sizes, int n_in,
                              void* d_out, int out_size, void* d_ws, size_t ws_size,
                              hipStream_t stream) {
    const float* h   = (const float*)d_in[0];
    const int*   adj = (const int*)d_in[1];
    const float* W   = (const float*)d_in[2];
    const float* a   = (const float*)d_in[3];
    float* out = (float*)d_out;

    float* Wh = (float*)d_ws;                 // 16384*256 floats = 16 MB
    float* f1 = Wh + 16384 * 256;             // 16384 floats
    float* f2 = f1 + 16384;                   // 16384 floats

    wh_gemm<<<dim3(256, 4), 256, 0, stream>>>(h, W, Wh);
    f12_kernel<<<4096, 256, 0, stream>>>(Wh, a, f1, f2);
    attn_kernel<<<dim3(64, 16), 256, 0, stream>>>(Wh, adj, f1, f2, out);
}

// Round 2
// 196.062 us; speedup vs baseline: 1.5843x; 1.5843x over previous
//
#include <hip/hip_runtime.h>

#define NEG_INF -1000000000.0f

typedef __attribute__((ext_vector_type(8))) short bf16x8;
typedef __attribute__((ext_vector_type(4))) float f32x4;

__device__ __forceinline__ unsigned short f2bf(float x) {
    unsigned int u = __float_as_uint(x);
    u += 0x7FFFu + ((u >> 16) & 1u);        // round-to-nearest-even
    return (unsigned short)(u >> 16);
}
__device__ __forceinline__ float bf2f(unsigned short s) {
    return __uint_as_float(((unsigned int)s) << 16);
}

// ---------------------------------------------------------------------------
// WbT[n][k] = bf16(W[k][n])  (256x256)
// ---------------------------------------------------------------------------
__global__ __launch_bounds__(256) void cast_wt(const float* __restrict__ W,
                                               short* __restrict__ WbT) {
    const int n = blockIdx.x, k = threadIdx.x;
    WbT[n * 256 + k] = (short)f2bf(W[k * 256 + n]);
}

// ---------------------------------------------------------------------------
// WhT[b][f][j] = bf16( (h @ W)[b,j,f] )  via MFMA 16x16x32.
// Block: 32 m-rows (nodes) x full N=256. 4 waves, wave w owns f-slice w*64..+63.
// ---------------------------------------------------------------------------
__global__ __launch_bounds__(256) void wh_gemm(const float* __restrict__ h,
                                               const short* __restrict__ WbT,
                                               short* __restrict__ WhT) {
    const int t = threadIdx.x;
    const int wid = t >> 6, lane = t & 63;
    const int quad = lane >> 4, l15 = lane & 15;
    const int m0 = blockIdx.x * 32;

    f32x4 acc[2][4] = {};

#pragma unroll
    for (int kt = 0; kt < 8; ++kt) {
        const int k0 = kt * 32;
        // A frags: h rows m0+rt*16+l15, k = k0 + quad*8 .. +8 (inline f32->bf16)
        bf16x8 a0, a1;
        {
            const float* p0 = h + (size_t)(m0 + l15) * 256 + k0 + quad * 8;
            const float* p1 = h + (size_t)(m0 + 16 + l15) * 256 + k0 + quad * 8;
            float4 x0 = *(const float4*)p0, y0 = *(const float4*)(p0 + 4);
            float4 x1 = *(const float4*)p1, y1 = *(const float4*)(p1 + 4);
            a0[0] = (short)f2bf(x0.x); a0[1] = (short)f2bf(x0.y);
            a0[2] = (short)f2bf(x0.z); a0[3] = (short)f2bf(x0.w);
            a0[4] = (short)f2bf(y0.x); a0[5] = (short)f2bf(y0.y);
            a0[6] = (short)f2bf(y0.z); a0[7] = (short)f2bf(y0.w);
            a1[0] = (short)f2bf(x1.x); a1[1] = (short)f2bf(x1.y);
            a1[2] = (short)f2bf(x1.z); a1[3] = (short)f2bf(x1.w);
            a1[4] = (short)f2bf(y1.x); a1[5] = (short)f2bf(y1.y);
            a1[6] = (short)f2bf(y1.z); a1[7] = (short)f2bf(y1.w);
        }
#pragma unroll
        for (int ft = 0; ft < 4; ++ft) {
            const int f = wid * 64 + ft * 16 + l15;
            bf16x8 bv = *(const bf16x8*)(WbT + (size_t)f * 256 + k0 + quad * 8);
            acc[0][ft] = __builtin_amdgcn_mfma_f32_16x16x32_bf16(a0, bv, acc[0][ft], 0, 0, 0);
            acc[1][ft] = __builtin_amdgcn_mfma_f32_16x16x32_bf16(a1, bv, acc[1][ft], 0, 0, 0);
        }
    }

    // Epilogue: C row (m) = quad*4+reg, col (n=f) = l15. Store transposed+bf16:
    // WhT[b][f][il], 4 consecutive nodes per lane -> one 8B store.
    const int b = m0 >> 10;
    const int il0 = (m0 & 1023) + quad * 4;
#pragma unroll
    for (int rt = 0; rt < 2; ++rt) {
#pragma unroll
        for (int ft = 0; ft < 4; ++ft) {
            const int f = wid * 64 + ft * 16 + l15;
            ushort4 pk;
            pk.x = f2bf(acc[rt][ft][0]);
            pk.y = f2bf(acc[rt][ft][1]);
            pk.z = f2bf(acc[rt][ft][2]);
            pk.w = f2bf(acc[rt][ft][3]);
            *(ushort4*)(WhT + ((size_t)b << 18) + (size_t)f * 1024 + il0 + rt * 16) = pk;
        }
    }
}

// ---------------------------------------------------------------------------
// f1[i] = sum_f WhT[b][f][il]*a1[f];  f2 likewise. Thread = node.
// ---------------------------------------------------------------------------
__global__ __launch_bounds__(256) void f12_kernel(const short* __restrict__ WhT,
                                                  const float* __restrict__ a,
                                                  float* __restrict__ f1,
                                                  float* __restrict__ f2) {
    const int i = blockIdx.x * 256 + threadIdx.x;
    const int b = i >> 10, il = i & 1023;
    const short* base = WhT + ((size_t)b << 18) + il;
    float s1 = 0.f, s2 = 0.f;
#pragma unroll 8
    for (int f = 0; f < 256; ++f) {
        float w = bf2f((unsigned short)base[(size_t)f << 10]);
        s1 += w * a[f];
        s2 += w * a[f + 256];
    }
    f1[i] = s1;
    f2[i] = s2;
}

// ---------------------------------------------------------------------------
// Flash-style single-pass attention + aggregation.
// Block: b = blockIdx.y, 32 i-rows at i0 = blockIdx.x*32. 4 waves.
// Wave w owns f-slice w*64..+63 -> acc[2 row-tiles][4 f-tiles] (16x16 frags).
// Score phase: wave w owns rows 8w..8w+7; 8 lanes per row, 16 j each.
// ---------------------------------------------------------------------------
__global__ __launch_bounds__(256) void attn_kernel(const short* __restrict__ WhT,
                                                   const int* __restrict__ adj,
                                                   const float* __restrict__ f1g,
                                                   const float* __restrict__ f2g,
                                                   float* __restrict__ out) {
    __shared__ float s_f2[1024];
    __shared__ short P[2][32][136];     // p tile, bf16, A-frag layout (stride 136)
    __shared__ float s_alpha[2][32];
    __shared__ float s_l[32];

    const int t = threadIdx.x;
    const int b = blockIdx.y;
    const int i0 = blockIdx.x * 32;
    const int wid = t >> 6, lane = t & 63;
    const int quad = lane >> 4, l15 = lane & 15;

    *(float4*)&s_f2[t * 4] = *(const float4*)&f2g[(b << 10) + t * 4];

    const int srow = wid * 8 + (lane >> 3);       // row this lane scores (0..31)
    const int scol = (lane & 7) * 4;              // j sub-offset
    const float f1r = f1g[(b << 10) + i0 + srow];
    const int* arow = adj + (size_t)((b << 10) + i0 + srow) * 1024;
    const short* whb = WhT + ((size_t)b << 18);

    float m_run = -3.0e38f, l_run = 0.0f;
    f32x4 acc[2][4] = {};

    __syncthreads();

    int buf = 0;
    for (int jt = 0; jt < 8; ++jt, buf ^= 1) {
        const int j0 = jt * 128;

        // ---- scores for this 32x128 tile
        float ev[16];
        float tmax = -3.0e38f;
#pragma unroll
        for (int c = 0; c < 4; ++c) {
            int4 av = *(const int4*)(arow + j0 + scol + 32 * c);
            float4 fv = *(const float4*)&s_f2[j0 + scol + 32 * c];
            float x0 = f1r + fv.x, x1 = f1r + fv.y;
            float x2 = f1r + fv.z, x3 = f1r + fv.w;
            float e0 = av.x ? fmaxf(x0, 0.2f * x0) : NEG_INF;
            float e1 = av.y ? fmaxf(x1, 0.2f * x1) : NEG_INF;
            float e2 = av.z ? fmaxf(x2, 0.2f * x2) : NEG_INF;
            float e3 = av.w ? fmaxf(x3, 0.2f * x3) : NEG_INF;
            ev[c * 4 + 0] = e0; ev[c * 4 + 1] = e1;
            ev[c * 4 + 2] = e2; ev[c * 4 + 3] = e3;
            tmax = fmaxf(tmax, fmaxf(fmaxf(e0, e1), fmaxf(e2, e3)));
        }
        tmax = fmaxf(tmax, __shfl_xor(tmax, 1));
        tmax = fmaxf(tmax, __shfl_xor(tmax, 2));
        tmax = fmaxf(tmax, __shfl_xor(tmax, 4));
        const float m_new = fmaxf(m_run, tmax);
        const float alpha = __expf(m_run - m_new);
        m_run = m_new;

        float rsum = 0.0f;
#pragma unroll
        for (int c = 0; c < 4; ++c) {
            ushort4 pk;
            pk.x = f2bf(__expf(ev[c * 4 + 0] - m_new));
            pk.y = f2bf(__expf(ev[c * 4 + 1] - m_new));
            pk.z = f2bf(__expf(ev[c * 4 + 2] - m_new));
            pk.w = f2bf(__expf(ev[c * 4 + 3] - m_new));
            rsum += bf2f(pk.x) + bf2f(pk.y) + bf2f(pk.z) + bf2f(pk.w);
            *(ushort4*)&P[buf][srow][scol + 32 * c] = pk;
        }
        rsum += __shfl_xor(rsum, 1);
        rsum += __shfl_xor(rsum, 2);
        rsum += __shfl_xor(rsum, 4);
        l_run = l_run * alpha + rsum;
        if ((lane & 7) == 0) s_alpha[buf][srow] = alpha;

        __syncthreads();   // P[buf] + s_alpha[buf] visible to all waves

        // ---- rescale accumulators by this tile's alpha (per C-frag row)
        float4 al0 = *(const float4*)&s_alpha[buf][quad * 4];
        float4 al1 = *(const float4*)&s_alpha[buf][16 + quad * 4];
#pragma unroll
        for (int ft = 0; ft < 4; ++ft) {
            acc[0][ft][0] *= al0.x; acc[0][ft][1] *= al0.y;
            acc[0][ft][2] *= al0.z; acc[0][ft][3] *= al0.w;
            acc[1][ft][0] *= al1.x; acc[1][ft][1] *= al1.y;
            acc[1][ft][2] *= al1.z; acc[1][ft][3] *= al1.w;
        }

        // ---- MFMA over this tile's 128 k (4 steps of 32)
#pragma unroll
        for (int kt = 0; kt < 4; ++kt) {
            bf16x8 a0 = *(const bf16x8*)&P[buf][l15][kt * 32 + quad * 8];
            bf16x8 a1 = *(const bf16x8*)&P[buf][16 + l15][kt * 32 + quad * 8];
#pragma unroll
            for (int ft = 0; ft < 4; ++ft) {
                const short* bp = whb + (size_t)(wid * 64 + ft * 16 + l15) * 1024
                                  + j0 + kt * 32 + quad * 8;
                bf16x8 bv = *(const bf16x8*)bp;
                acc[0][ft] = __builtin_amdgcn_mfma_f32_16x16x32_bf16(a0, bv, acc[0][ft], 0, 0, 0);
                acc[1][ft] = __builtin_amdgcn_mfma_f32_16x16x32_bf16(a1, bv, acc[1][ft], 0, 0, 0);
            }
        }
        // no second barrier: next tile writes the other P/alpha buffer.
    }

    if ((lane & 7) == 0) s_l[srow] = l_run;
    __syncthreads();

    float4 lv0 = *(const float4*)&s_l[quad * 4];
    float4 lv1 = *(const float4*)&s_l[16 + quad * 4];
    const float n00 = 1.0f / lv0.x, n01 = 1.0f / lv0.y, n02 = 1.0f / lv0.z, n03 = 1.0f / lv0.w;
    const float n10 = 1.0f / lv1.x, n11 = 1.0f / lv1.y, n12 = 1.0f / lv1.z, n13 = 1.0f / lv1.w;

#pragma unroll
    for (int ft = 0; ft < 4; ++ft) {
        const int f = wid * 64 + ft * 16 + l15;
        float* op0 = out + (size_t)((b << 10) + i0 + quad * 4) * 256 + f;
        op0[0]       = acc[0][ft][0] * n00;
        op0[256]     = acc[0][ft][1] * n01;
        op0[512]     = acc[0][ft][2] * n02;
        op0[768]     = acc[0][ft][3] * n03;
        float* op1 = out + (size_t)((b << 10) + i0 + 16 + quad * 4) * 256 + f;
        op1[0]       = acc[1][ft][0] * n10;
        op1[256]     = acc[1][ft][1] * n11;
        op1[512]     = acc[1][ft][2] * n12;
        op1[768]     = acc[1][ft][3] * n13;
    }
}

// ---------------------------------------------------------------------------
extern "C" void kernel_launch(void* const* d_in, const int* in_sizes, int n_in,
                              void* d_out, int out_size, void* d_ws, size_t ws_size,
                              hipStream_t stream) {
    const float* h   = (const float*)d_in[0];
    const int*   adj = (const int*)d_in[1];
    const float* W   = (const float*)d_in[2];
    const float* a   = (const float*)d_in[3];
    float* out = (float*)d_out;

    short* WbT = (short*)d_ws;                    // 256*256 bf16     = 128 KB
    short* WhT = WbT + 65536;                     // 16*256*1024 bf16 = 8 MB
    float* f1  = (float*)(WhT + 16 * 1024 * 256); // 16384 f32
    float* f2  = f1 + 16384;                      // 16384 f32

    cast_wt<<<256, 256, 0, stream>>>(W, WbT);
    wh_gemm<<<512, 256, 0, stream>>>(h, WbT, WhT);
    f12_kernel<<<64, 256, 0, stream>>>(WhT, a, f1, f2);
    attn_kernel<<<dim3(32, 16), 256, 0, stream>>>(WhT, adj, f1, f2, out);
}